// Round 2
// baseline (305.417 us; speedup 1.0000x reference)
//
#include <hip/hip_runtime.h>

// PointPillarsScatter: out[b][c][y][x] = feat[m][c] for the LAST point m
// (numpy last-write-wins) with coords (b, _, y, x); 0 elsewhere.
//
// Pass 1: winner[slot] = atomicMax(point index)  (max m == last write wins)
// Pass 2: branchless gather — each thread owns 4 consecutive x of one (b,y),
//         selects per-slot a row pointer (feat row, or a zeroed 256 B row in
//         ws for empty slots), then runs a fully-unrolled loop of
//         unconditional float4 loads + 4x4 register transpose + coalesced
//         float4 stores (1 KiB/wave/store). No branches in the hot loop.

#define NXc 512
#define NYc 512
#define Cc  64

__global__ void __launch_bounds__(256)
winners_kernel(const int* __restrict__ coords, int* __restrict__ winner, int M) {
    int m = blockIdx.x * blockDim.x + threadIdx.x;
    if (m >= M) return;
    int4 cd = ((const int4*)coords)[m];          // [b, z, y, x]
    int slot = cd.x * (NYc * NXc) + cd.z * NXc + cd.w;
    atomicMax(&winner[slot], m);                 // device-scope default
}

__global__ void __launch_bounds__(256)
gather_kernel(const float* __restrict__ feat, const int* __restrict__ winner,
              const float* __restrict__ zrow, float* __restrict__ out) {
    int tid = blockIdx.x * blockDim.x + threadIdx.x;   // 0 .. B*NY*NX/4-1
    int x4 = (tid & (NXc / 4 - 1)) * 4;                // 0..508 step 4
    int by = tid >> 7;                                 // NX/4 = 128
    int y  = by & (NYc - 1);
    int b  = by >> 9;
    const int plane = NYc * NXc;                       // 262144

    int4 w = *(const int4*)(winner + b * plane + y * NXc + x4);

    // Branchless: empty slot -> pointer to an all-zero 256 B row (L1-resident
    // broadcast for all empty lanes). Occupied -> the pillar's feature row.
    const float* p0 = (w.x >= 0) ? (feat + (size_t)w.x * Cc) : zrow;
    const float* p1 = (w.y >= 0) ? (feat + (size_t)w.y * Cc) : zrow;
    const float* p2 = (w.z >= 0) ? (feat + (size_t)w.z * Cc) : zrow;
    const float* p3 = (w.w >= 0) ? (feat + (size_t)w.w * Cc) : zrow;

    float* obase = out + (size_t)(b * Cc) * plane + y * NXc + x4;

    #pragma unroll
    for (int cg = 0; cg < Cc / 4; ++cg) {
        float4 f0 = *(const float4*)(p0 + cg * 4);
        float4 f1 = *(const float4*)(p1 + cg * 4);
        float4 f2 = *(const float4*)(p2 + cg * 4);
        float4 f3 = *(const float4*)(p3 + cg * 4);
        float4 o;
        o = make_float4(f0.x, f1.x, f2.x, f3.x);
        *(float4*)(obase + (size_t)(cg * 4 + 0) * plane) = o;
        o = make_float4(f0.y, f1.y, f2.y, f3.y);
        *(float4*)(obase + (size_t)(cg * 4 + 1) * plane) = o;
        o = make_float4(f0.z, f1.z, f2.z, f3.z);
        *(float4*)(obase + (size_t)(cg * 4 + 2) * plane) = o;
        o = make_float4(f0.w, f1.w, f2.w, f3.w);
        *(float4*)(obase + (size_t)(cg * 4 + 3) * plane) = o;
    }
}

extern "C" void kernel_launch(void* const* d_in, const int* in_sizes, int n_in,
                              void* d_out, int out_size, void* d_ws, size_t ws_size,
                              hipStream_t stream) {
    const float* feat   = (const float*)d_in[0];
    const int*   coords = (const int*)d_in[1];
    float*       out    = (float*)d_out;

    const int M = in_sizes[1] / 4;                 // coordinates is (M,4)
    const int B = out_size / (Cc * NYc * NXc);     // 4

    int* winner = (int*)d_ws;                      // B*NY*NX ints = 4 MiB
    const size_t wbytes = (size_t)B * NYc * NXc * sizeof(int);
    float* zrow = (float*)((char*)d_ws + wbytes);  // 256 B zero row

    // ws is re-poisoned (0xAA) before every timed launch -> must re-init.
    hipMemsetAsync(winner, 0xFF, wbytes, stream);          // winner = -1
    hipMemsetAsync(zrow, 0, Cc * sizeof(float), stream);   // zero row

    winners_kernel<<<(M + 255) / 256, 256, 0, stream>>>(coords, winner, M);

    const int nthreads = B * NYc * NXc / 4;        // 262144
    gather_kernel<<<nthreads / 256, 256, 0, stream>>>(feat, winner, zrow, out);
}

// Round 3
// 297.217 us; speedup vs baseline: 1.0276x; 1.0276x over previous
//
#include <hip/hip_runtime.h>

// PointPillarsScatter: out[b][c][y][x] = feat[m][c] for the LAST point m
// (numpy last-write-wins) with coords (b, _, y, x); 0 elsewhere.
//
// Pass 1: winner[slot] = atomicMax(point index)  (max m == last write wins)
// Pass 2: gather, channel-split for occupancy: each thread owns 4 consecutive
//         x of one (b,y) and a 16-channel group (one 64 B feat line per row).
//         4x more threads / 4x shorter chains than the 64-ch/thread version:
//         better latency hiding + HBM channel mixing. All stores are
//         coalesced float4 (1 KiB/wave/store).

#define NXc 512
#define NYc 512
#define Cc  64
#define CG  16   // channels per thread

__global__ void __launch_bounds__(256)
winners_kernel(const int* __restrict__ coords, int* __restrict__ winner, int M) {
    int m = blockIdx.x * blockDim.x + threadIdx.x;
    if (m >= M) return;
    int4 cd = ((const int4*)coords)[m];          // [b, z, y, x]
    int slot = cd.x * (NYc * NXc) + cd.z * NXc + cd.w;
    atomicMax(&winner[slot], m);                 // device-scope default
}

__global__ void __launch_bounds__(256)
gather_kernel(const float* __restrict__ feat, const int* __restrict__ winner,
              const float* __restrict__ zrow, float* __restrict__ out) {
    int tid = blockIdx.x * blockDim.x + threadIdx.x;   // 0 .. B*NY*NX/4-1
    int x4 = (tid & (NXc / 4 - 1)) * 4;                // 0..508 step 4
    int by = tid >> 7;                                 // NX/4 = 128
    int y  = by & (NYc - 1);
    int b  = by >> 9;
    int c0 = blockIdx.y * CG;                          // channel group base
    const int plane = NYc * NXc;                       // 262144

    int4 w = *(const int4*)(winner + b * plane + y * NXc + x4);

    // Row base pointers, offset to this thread's channel group. Empty slot ->
    // zero row in ws (L1-resident broadcast).
    const float* p0 = ((w.x >= 0) ? (feat + (size_t)w.x * Cc) : zrow) + c0;
    const float* p1 = ((w.y >= 0) ? (feat + (size_t)w.y * Cc) : zrow) + c0;
    const float* p2 = ((w.z >= 0) ? (feat + (size_t)w.z * Cc) : zrow) + c0;
    const float* p3 = ((w.w >= 0) ? (feat + (size_t)w.w * Cc) : zrow) + c0;

    float* obase = out + (size_t)(b * Cc + c0) * plane + y * NXc + x4;

    #pragma unroll
    for (int j = 0; j < CG / 4; ++j) {
        float4 f0 = *(const float4*)(p0 + j * 4);
        float4 f1 = *(const float4*)(p1 + j * 4);
        float4 f2 = *(const float4*)(p2 + j * 4);
        float4 f3 = *(const float4*)(p3 + j * 4);
        float4 o;
        o = make_float4(f0.x, f1.x, f2.x, f3.x);
        *(float4*)(obase + (size_t)(j * 4 + 0) * plane) = o;
        o = make_float4(f0.y, f1.y, f2.y, f3.y);
        *(float4*)(obase + (size_t)(j * 4 + 1) * plane) = o;
        o = make_float4(f0.z, f1.z, f2.z, f3.z);
        *(float4*)(obase + (size_t)(j * 4 + 2) * plane) = o;
        o = make_float4(f0.w, f1.w, f2.w, f3.w);
        *(float4*)(obase + (size_t)(j * 4 + 3) * plane) = o;
    }
}

extern "C" void kernel_launch(void* const* d_in, const int* in_sizes, int n_in,
                              void* d_out, int out_size, void* d_ws, size_t ws_size,
                              hipStream_t stream) {
    const float* feat   = (const float*)d_in[0];
    const int*   coords = (const int*)d_in[1];
    float*       out    = (float*)d_out;

    const int M = in_sizes[1] / 4;                 // coordinates is (M,4)
    const int B = out_size / (Cc * NYc * NXc);     // 4

    int* winner = (int*)d_ws;                      // B*NY*NX ints = 4 MiB
    const size_t wbytes = (size_t)B * NYc * NXc * sizeof(int);
    float* zrow = (float*)((char*)d_ws + wbytes);  // 256 B zero row

    // ws is re-poisoned (0xAA) before every timed launch -> must re-init.
    hipMemsetAsync(winner, 0xFF, wbytes, stream);          // winner = -1
    hipMemsetAsync(zrow, 0, Cc * sizeof(float), stream);   // zero row

    winners_kernel<<<(M + 255) / 256, 256, 0, stream>>>(coords, winner, M);

    dim3 grid(B * NYc * NXc / 4 / 256, Cc / CG);   // (1024, 4)
    gather_kernel<<<grid, 256, 0, stream>>>(feat, winner, zrow, out);
}